// Round 1
// baseline (464.537 us; speedup 1.0000x reference)
//
#include <hip/hip_runtime.h>

typedef unsigned short u16;
typedef __attribute__((ext_vector_type(8))) short short8;
typedef __attribute__((ext_vector_type(4))) float f32x4;

constexpr int BATCH = 8, CC = 128, CE = 256, DIM = 128, NTOK = 4096;

#define DEV static __device__ __forceinline__

DEV u16 f2bf(float f) {
    union { float f; unsigned u; } v; v.f = f;
    unsigned r = (v.u + 0x7fffu + ((v.u >> 16) & 1u)) >> 16;
    return (u16)r;
}
DEV float bf2f(u16 h) {
    union { unsigned u; float f; } v; v.u = ((unsigned)h) << 16;
    return v.f;
}

// ---------------------------------------------------------------------------
// Kernel 1: fused QKV projection. fp32 compute, bf16 outputs.
// Q,K stored [B][N][D]; V stored [B][D][N].
// ---------------------------------------------------------------------------
template <int CTOT, bool TRANS>
__device__ void proj_pass(const float* __restrict__ X, const float* __restrict__ W,
                          const float* __restrict__ bias, u16* __restrict__ dst,
                          int b, int nbase, float* sX, float* sW)
{
    const int tid = threadIdx.x;
    const int nl = tid & 15, cg = tid >> 4;
    const int n0 = nl * 4, d0 = cg * 8;

    float acc[4][8];
#pragma unroll
    for (int i = 0; i < 4; ++i)
#pragma unroll
        for (int j = 0; j < 8; ++j) acc[i][j] = 0.f;

    for (int cb = 0; cb < CTOT; cb += 64) {
        __syncthreads();
        // stage X chunk [64c][64n]  (coalesced rows)
#pragma unroll
        for (int i = 0; i < 16; ++i) {
            int idx = tid + 256 * i;
            int c = idx >> 6, n = idx & 63;
            sX[idx] = X[((size_t)b * CTOT + cb + c) * NTOK + nbase + n];
        }
        // stage W chunk transposed [64c][128d]
#pragma unroll
        for (int i = 0; i < 32; ++i) {
            int idx = tid + 256 * i;
            int c = idx >> 7, d = idx & 127;
            sW[c * 128 + d] = W[(size_t)d * CTOT + cb + c];
        }
        __syncthreads();
#pragma unroll 2
        for (int c = 0; c < 64; ++c) {
            const float4 x  = *(const float4*)&sX[c * 64 + n0];
            const float4 wa = *(const float4*)&sW[c * 128 + d0];
            const float4 wb = *(const float4*)&sW[c * 128 + d0 + 4];
#pragma unroll
            for (int i = 0; i < 4; ++i) {
                const float xv = (&x.x)[i];
                acc[i][0] += xv * wa.x; acc[i][1] += xv * wa.y;
                acc[i][2] += xv * wa.z; acc[i][3] += xv * wa.w;
                acc[i][4] += xv * wb.x; acc[i][5] += xv * wb.y;
                acc[i][6] += xv * wb.z; acc[i][7] += xv * wb.w;
            }
        }
    }
    float bb[8];
#pragma unroll
    for (int j = 0; j < 8; ++j) bb[j] = bias[d0 + j];

    if (!TRANS) {
#pragma unroll
        for (int i = 0; i < 4; ++i) {
            short8 o;
#pragma unroll
            for (int j = 0; j < 8; ++j) o[j] = (short)f2bf(acc[i][j] + bb[j]);
            *(short8*)&dst[((size_t)b * NTOK + nbase + n0 + i) * DIM + d0] = o;
        }
    } else {
#pragma unroll
        for (int j = 0; j < 8; ++j) {
            ushort4 o;
            o.x = f2bf(acc[0][j] + bb[j]); o.y = f2bf(acc[1][j] + bb[j]);
            o.z = f2bf(acc[2][j] + bb[j]); o.w = f2bf(acc[3][j] + bb[j]);
            *(ushort4*)&dst[((size_t)b * DIM + d0 + j) * NTOK + nbase + n0] = o;
        }
    }
}

__global__ __launch_bounds__(256)
void qkv_proj_kernel(const float* __restrict__ cape, const float* __restrict__ era5,
                     const float* __restrict__ Wq, const float* __restrict__ bq,
                     const float* __restrict__ Wk, const float* __restrict__ bk,
                     const float* __restrict__ Wv, const float* __restrict__ bv,
                     u16* __restrict__ Qb, u16* __restrict__ Kb, u16* __restrict__ Vb)
{
    __shared__ __align__(16) float sX[64 * 64];
    __shared__ __align__(16) float sW[64 * 128];
    const int b = blockIdx.y;
    const int nbase = blockIdx.x * 64;
    proj_pass<CC, false>(cape, Wq, bq, Qb, b, nbase, sX, sW);
    proj_pass<CE, false>(era5, Wk, bk, Kb, b, nbase, sX, sW);
    proj_pass<CE, true >(era5, Wv, bv, Vb, b, nbase, sX, sW);
}

// ---------------------------------------------------------------------------
// Kernel 2: flash attention. Q,K [B][N][D] bf16, V [B][D][N] bf16 -> AO [B][N][D] bf16.
// 4 waves x 16 q-rows, KBLK=64, mfma_f32_16x16x32_bf16.
// C-frag layout (m89): col = lane&15, row = (lane>>4)*4 + reg.
// A-frag: A[row=lane&15][k=(lane>>4)*8+j]; B-frag: B[k=(lane>>4)*8+j][col=lane&15].
// ---------------------------------------------------------------------------
__global__ __launch_bounds__(256)
void attn_kernel(const u16* __restrict__ Qg, const u16* __restrict__ Kg,
                 const u16* __restrict__ Vg, u16* __restrict__ AO)
{
    __shared__ __align__(16) u16 sK[64 * 128];      // row k, 16B-chunk swizzle c^=(k&7)
    __shared__ __align__(16) u16 sV[128 * 64];      // row d, chunk swizzle c^=(d&7)
    __shared__ __align__(16) u16 sP[4][16][72];     // per-wave P tile, stride 72 (pad 8)

    const int tid = threadIdx.x;
    const int b = blockIdx.y;
    const int qbase = blockIdx.x * 64;
    const int lane = tid & 63, w = tid >> 6;
    const int col = lane & 15, g = lane >> 4;

    const float kScale = 0.088388347648318447f * 1.4426950408889634f; // 1/sqrt(128)*log2(e)

    // ---- stage Q tile (through sK buffer, swizzled) and read A-frags
#pragma unroll
    for (int i = 0; i < 4; ++i) {
        int chunk = tid + 256 * i;
        int row = chunk >> 4, c = chunk & 15;
        uint4 v = *(const uint4*)&Qg[((size_t)b * NTOK + qbase + row) * DIM + c * 8];
        *(uint4*)&sK[row * 128 + (c ^ (row & 7)) * 8] = v;
    }
    __syncthreads();
    short8 aQ[4];
    {
        const int qr = w * 16 + col;
#pragma unroll
        for (int dc = 0; dc < 4; ++dc) {
            int c2 = (dc * 4 + g) ^ (qr & 7);
            aQ[dc] = *(const short8*)&sK[qr * 128 + c2 * 8];
        }
    }
    __syncthreads();

    f32x4 O[8];
#pragma unroll
    for (int i = 0; i < 8; ++i)
#pragma unroll
        for (int r = 0; r < 4; ++r) O[i][r] = 0.f;
    float m_run[4], l_run[4];
#pragma unroll
    for (int r = 0; r < 4; ++r) { m_run[r] = -1e30f; l_run[r] = 0.f; }

    for (int t = 0; t < NTOK / 64; ++t) {
        // ---- stage K tile [64k][128d] swizzled
#pragma unroll
        for (int i = 0; i < 4; ++i) {
            int chunk = tid + 256 * i;
            int row = chunk >> 4, c = chunk & 15;
            uint4 v = *(const uint4*)&Kg[((size_t)b * NTOK + t * 64 + row) * DIM + c * 8];
            *(uint4*)&sK[row * 128 + (c ^ (row & 7)) * 8] = v;
        }
        // ---- stage V tile [128d][64k] swizzled
#pragma unroll
        for (int i = 0; i < 4; ++i) {
            int chunk = tid + 256 * i;
            int dr = chunk >> 3, c = chunk & 7;
            uint4 v = *(const uint4*)&Vg[((size_t)b * DIM + dr) * NTOK + t * 64 + c * 8];
            *(uint4*)&sV[dr * 64 + (c ^ (dr & 7)) * 8] = v;
        }
        __syncthreads();

        // ---- S = Q K^T  (4 k-subtiles x 4 d-chunks)
        f32x4 S[4];
#pragma unroll
        for (int s = 0; s < 4; ++s)
#pragma unroll
            for (int r = 0; r < 4; ++r) S[s][r] = 0.f;
#pragma unroll
        for (int s = 0; s < 4; ++s) {
            const int krow = s * 16 + col;
#pragma unroll
            for (int dc = 0; dc < 4; ++dc) {
                int c2 = (dc * 4 + g) ^ (krow & 7);
                short8 bK = *(const short8*)&sK[krow * 128 + c2 * 8];
                S[s] = __builtin_amdgcn_mfma_f32_16x16x32_bf16(aQ[dc], bK, S[s], 0, 0, 0);
            }
        }

        // ---- online softmax (log2 domain). Lane (g,col) owns q rows 4g..4g+3.
        float mx[4];
#pragma unroll
        for (int r = 0; r < 4; ++r)
            mx[r] = fmaxf(fmaxf(S[0][r], S[1][r]), fmaxf(S[2][r], S[3][r])) * kScale;
#pragma unroll
        for (int off = 1; off < 16; off <<= 1)
#pragma unroll
            for (int r = 0; r < 4; ++r)
                mx[r] = fmaxf(mx[r], __shfl_xor(mx[r], off, 64));

        float fs[4];
#pragma unroll
        for (int r = 0; r < 4; ++r) {
            float mn = fmaxf(m_run[r], mx[r]);
            fs[r] = exp2f(m_run[r] - mn);
            m_run[r] = mn;
        }
        float P[4][4], rs[4];
#pragma unroll
        for (int s = 0; s < 4; ++s)
#pragma unroll
            for (int r = 0; r < 4; ++r)
                P[s][r] = exp2f(S[s][r] * kScale - m_run[r]);
#pragma unroll
        for (int r = 0; r < 4; ++r) rs[r] = P[0][r] + P[1][r] + P[2][r] + P[3][r];
#pragma unroll
        for (int off = 1; off < 16; off <<= 1)
#pragma unroll
            for (int r = 0; r < 4; ++r) rs[r] += __shfl_xor(rs[r], off, 64);
#pragma unroll
        for (int r = 0; r < 4; ++r) l_run[r] = l_run[r] * fs[r] + rs[r];

        // rescale O accumulators
#pragma unroll
        for (int i = 0; i < 8; ++i)
#pragma unroll
            for (int r = 0; r < 4; ++r) O[i][r] *= fs[r];

        // ---- write P (bf16) to per-wave LDS tile [16q][64k]
#pragma unroll
        for (int s = 0; s < 4; ++s)
#pragma unroll
            for (int r = 0; r < 4; ++r)
                sP[w][g * 4 + r][s * 16 + col] = f2bf(P[s][r]);

        // ---- O += P V
#pragma unroll
        for (int kc = 0; kc < 2; ++kc) {
            short8 aP = *(const short8*)&sP[w][col][kc * 32 + g * 8];
#pragma unroll
            for (int dc2 = 0; dc2 < 8; ++dc2) {
                const int dr = dc2 * 16 + col;
                int c2 = (kc * 4 + g) ^ (dr & 7);
                short8 bV = *(const short8*)&sV[dr * 64 + c2 * 8];
                O[dc2] = __builtin_amdgcn_mfma_f32_16x16x32_bf16(aP, bV, O[dc2], 0, 0, 0);
            }
        }
        __syncthreads();
    }

    // ---- epilogue: normalize and store AO[b][q][d] bf16
    float inv[4];
#pragma unroll
    for (int r = 0; r < 4; ++r) inv[r] = 1.f / l_run[r];
#pragma unroll
    for (int dc2 = 0; dc2 < 8; ++dc2)
#pragma unroll
        for (int r = 0; r < 4; ++r) {
            int q = qbase + w * 16 + g * 4 + r;
            AO[((size_t)b * NTOK + q) * DIM + dc2 * 16 + col] = f2bf(O[dc2][r] * inv[r]);
        }
}

// ---------------------------------------------------------------------------
// Kernel 3: output projection. out[b][co][n] = Wo @ AO[b][n][:] + bo
// ---------------------------------------------------------------------------
__global__ __launch_bounds__(256)
void oproj_kernel(const u16* __restrict__ AO, const float* __restrict__ Wo,
                  const float* __restrict__ bo, float* __restrict__ Out)
{
    __shared__ __align__(16) u16 sA[128 * 72];   // [d][n] transposed, stride 72
    __shared__ __align__(16) u16 sW[128 * 128];  // [d][co], Wo as bf16

    const int tid = threadIdx.x;
    const int b = blockIdx.y;
    const int nbase = blockIdx.x * 64;

    // stage Wo transposed (coalesced global read; LDS write conflicts are one-time)
#pragma unroll 4
    for (int i = 0; i < 64; ++i) {
        int idx = tid + 256 * i;
        int d = idx & 127, co = idx >> 7;
        sW[d * 128 + co] = f2bf(Wo[(size_t)co * DIM + d]);
    }
    // stage AO tile transposed [d][n]
#pragma unroll
    for (int i = 0; i < 4; ++i) {
        int idx = tid + 256 * i;
        int c = idx & 15, n = idx >> 4;
        uint4 v = *(const uint4*)&AO[((size_t)b * NTOK + nbase + n) * DIM + c * 8];
        unsigned tmp[4] = {v.x, v.y, v.z, v.w};
#pragma unroll
        for (int j = 0; j < 8; ++j)
            sA[(c * 8 + j) * 72 + n] = (u16)(tmp[j >> 1] >> ((j & 1) * 16));
    }
    __syncthreads();

    const int nl = tid & 15, cg = tid >> 4;
    const int n0 = nl * 4, co0 = cg * 8;
    float acc[4][8];
#pragma unroll
    for (int i = 0; i < 4; ++i)
#pragma unroll
        for (int j = 0; j < 8; ++j) acc[i][j] = 0.f;

#pragma unroll 4
    for (int d = 0; d < 128; ++d) {
        ushort4 xs = *(const ushort4*)&sA[d * 72 + n0];
        short8 wv  = *(const short8*)&sW[d * 128 + co0];
        float x[4] = {bf2f(xs.x), bf2f(xs.y), bf2f(xs.z), bf2f(xs.w)};
        float wf[8];
#pragma unroll
        for (int j = 0; j < 8; ++j) wf[j] = bf2f((u16)wv[j]);
#pragma unroll
        for (int i = 0; i < 4; ++i)
#pragma unroll
            for (int j = 0; j < 8; ++j) acc[i][j] += x[i] * wf[j];
    }

#pragma unroll
    for (int j = 0; j < 8; ++j) {
        float bb = bo[co0 + j];
        float4 o = {acc[0][j] + bb, acc[1][j] + bb, acc[2][j] + bb, acc[3][j] + bb};
        *(float4*)&Out[((size_t)b * DIM + co0 + j) * NTOK + nbase + n0] = o;
    }
}

// ---------------------------------------------------------------------------
extern "C" void kernel_launch(void* const* d_in, const int* in_sizes, int n_in,
                              void* d_out, int out_size, void* d_ws, size_t ws_size,
                              hipStream_t stream)
{
    const float* cape = (const float*)d_in[0];
    const float* era5 = (const float*)d_in[1];
    const float* Wq = (const float*)d_in[2];
    const float* bq = (const float*)d_in[3];
    const float* Wk = (const float*)d_in[4];
    const float* bk = (const float*)d_in[5];
    const float* Wv = (const float*)d_in[6];
    const float* bv = (const float*)d_in[7];
    const float* Wo = (const float*)d_in[8];
    const float* bo = (const float*)d_in[9];

    u16* Qb = (u16*)d_ws;
    u16* Kb = Qb + (size_t)BATCH * NTOK * DIM;
    u16* Vb = Kb + (size_t)BATCH * NTOK * DIM;
    u16* AO = Vb + (size_t)BATCH * NTOK * DIM;

    dim3 grid(NTOK / 64, BATCH), blk(256);
    hipLaunchKernelGGL(qkv_proj_kernel, grid, blk, 0, stream,
                       cape, era5, Wq, bq, Wk, bk, Wv, bv, Qb, Kb, Vb);
    hipLaunchKernelGGL(attn_kernel, grid, blk, 0, stream, Qb, Kb, Vb, AO);
    hipLaunchKernelGGL(oproj_kernel, grid, blk, 0, stream, AO, Wo, bo, (float*)d_out);
}